// Round 16
// baseline (340.898 us; speedup 1.0000x reference)
//
#include <hip/hip_runtime.h>
#include <hip/hip_bf16.h>
#include <stdint.h>

typedef __bf16 bf16x8 __attribute__((ext_vector_type(8)));
typedef float  f32x4  __attribute__((ext_vector_type(4)));
typedef float  f32x16 __attribute__((ext_vector_type(16)));

static constexpr float kScale = 0.0078125f;  // 1/128

// ---------- f32 -> bf16 (RNE) convert ----------
static __device__ __forceinline__ uint32_t bf16_rne(float f) {
  uint32_t u = __builtin_bit_cast(uint32_t, f);
  u += 0x7FFFu + ((u >> 16) & 1u);
  return u >> 16;
}
static __device__ __forceinline__ uint32_t pack2(float lo, float hi) {
  return bf16_rne(lo) | (bf16_rne(hi) << 16);
}

__global__ __launch_bounds__(256) void cvt_fused(
    const float* __restrict__ x, const float* __restrict__ w,
    uint4* __restrict__ dst, long nx8) {
  const long i = (long)blockIdx.x * 256 + threadIdx.x;
  const float4* sv;
  long j;
  if (i < nx8) { sv = reinterpret_cast<const float4*>(x); j = i; }
  else         { sv = reinterpret_cast<const float4*>(w); j = i - nx8; }
  float4 a = sv[2 * j];
  float4 b = sv[2 * j + 1];
  uint4 o;
  o.x = pack2(a.x, a.y);
  o.y = pack2(a.z, a.w);
  o.z = pack2(b.x, b.y);
  o.w = pack2(b.z, b.w);
  dst[i] = o;
}

__global__ __launch_bounds__(256) void cvt_f32_to_bf16(
    const float* __restrict__ src, uint4* __restrict__ dst) {
  const int i = blockIdx.x * 256 + threadIdx.x;
  const float4* sv = reinterpret_cast<const float4*>(src);
  float4 a = sv[2 * i];
  float4 b = sv[2 * i + 1];
  uint4 o;
  o.x = pack2(a.x, a.y);
  o.y = pack2(a.z, a.w);
  o.z = pack2(b.x, b.y);
  o.w = pack2(b.z, b.w);
  dst[i] = o;
}

// ---------- async global->LDS, 16B per lane ----------
static __device__ __forceinline__ void gload_lds16(const void* g, void* l) {
  __builtin_amdgcn_global_load_lds(
      (const __attribute__((address_space(1))) void*)g,
      (__attribute__((address_space(3))) void*)l, 16, 0, 0);
}

#define BARRIER() __builtin_amdgcn_s_barrier()
#define VMW(n) asm volatile("s_waitcnt vmcnt(" #n ")" ::: "memory")

// =====================================================================
// R16: 128x128 tile, BK=64, 256 threads (4 waves 2Mx2N, per-wave 64x64),
// LDS 64 KB -> TWO BLOCKS PER CU (independent barrier domains fill each
// other's barrier/vmcnt/prologue/epilogue stalls -- the measured 11k-cyc
// iter vs ~2.2k pipe floor is stall time, not pipe time).
// 4 phases per 2-tile iter; barrier AFTER each MFMA cluster (R11);
// stride-8-aware swizzle (R12 algebra, identical 128B-row geometry);
// stages one-barrier-after-last-reader; VMW(6) at P2/P4:
//   outstanding = 14 -> forces exactly the 8 loads of the next-read tile.
// =====================================================================
constexpr int TV128 = (128 * 64) / 8;  // bf16x8 vectors per buffer

template <int MT>
__device__ __forceinline__ void quad2(f32x16 (&acc)[2][2],
                                      const bf16x8 (&aF)[4],
                                      const bf16x8 (&bF)[2][4]) {
  __builtin_amdgcn_s_setprio(1);
#pragma unroll
  for (int ks = 0; ks < 4; ++ks)
#pragma unroll
    for (int nt = 0; nt < 2; ++nt)
      acc[MT][nt] = __builtin_amdgcn_mfma_f32_32x32x16_bf16(
          aF[ks], bF[nt][ks], acc[MT][nt], 0, 0, 0);
  __builtin_amdgcn_s_setprio(0);
}

// read slot for k-block (ks,lk): (ks<<1) ^ erk,
// erk = l7 ^ ((l31>>3)&3) ^ lk ^ (lk<<2)   (R12 involution, verified)
template <int BUF, int MT>
__device__ __forceinline__ void loadAmt(bf16x8 (&aF)[4], const bf16x8* Av,
                                        int wr, int l31, int erk) {
  const int row = (wr << 6) + (MT << 5) + l31;
#pragma unroll
  for (int ks = 0; ks < 4; ++ks)
    aF[ks] = Av[BUF * TV128 + row * 8 + ((ks << 1) ^ erk)];
}
template <int BUF>
__device__ __forceinline__ void loadBall(bf16x8 (&bF)[2][4], const bf16x8* Bv,
                                         int wc, int l31, int erk) {
#pragma unroll
  for (int nt = 0; nt < 2; ++nt) {
    const int row = (wc << 6) + (nt << 5) + l31;
#pragma unroll
    for (int ks = 0; ks < 4; ++ks)
      bF[nt][ks] = Bv[BUF * TV128 + row * 8 + ((ks << 1) ^ erk)];
  }
}

__global__ __launch_bounds__(256, 2) void gemm128_2ph(
    const uint16_t* __restrict__ A, const uint16_t* __restrict__ B,
    const float* __restrict__ bias, float* __restrict__ C,
    int Mi, int Ni, int Ki) {
  __shared__ __align__(16) uint16_t As[2][128 * 64];  // 16 KB each
  __shared__ __align__(16) uint16_t Bs[2][128 * 64];  // 16 KB each -> 64 KB

  const int tid = threadIdx.x;
  const int l   = tid & 63;
  const int wv  = tid >> 6;   // 0..3
  const int wr  = wv >> 1;    // 0..1
  const int wc  = wv & 1;     // 0..1
  const int l31 = l & 31;
  const int lk  = l >> 5;
  const int l8  = l >> 3;
  const int l7  = l & 7;
  const int erk = l7 ^ ((l31 >> 3) & 3) ^ lk ^ (lk << 2);

  const int nbm = Mi >> 7, nbn = Ni >> 7;
  const int nwg = nbm * nbn;
  const int q = nwg >> 3, r = nwg & 7;
  const int xcd = (int)blockIdx.x & 7, orig = (int)blockIdx.x >> 3;
  const int swz = (xcd < r ? xcd * (q + 1) : r * (q + 1) + (xcd - r) * q) + orig;

  // 8bm x 4bn super-tile mapping (32-block groups, L2 dedup)
  int bm, bn;
  if ((nbm & 7) == 0 && (nbn & 3) == 0) {
    const int s = swz >> 5;
    const int o = swz & 31;
    const int nsc = nbn >> 2;
    bm = (s / nsc) * 8 + (o >> 2);
    bn = (s % nsc) * 4 + (o & 3);
  } else {
    bm = swz / nbn;
    bn = swz % nbn;
  }

  // staging: one instr = 32 rows x 64 cols; lane row = chunk + wv*8 + l8;
  // inverse-swizzled global source: u0 = l7^l8^wv; kb = u0^((u0&1)<<2).
  const int u0   = l7 ^ l8 ^ wv;
  const int xcol = (u0 ^ ((u0 & 1) << 2)) << 3;
  const uint16_t* gA0 = A + (size_t)((bm << 7) + (wv << 3) + l8) * Ki + xcol;
  const uint16_t* gB0 = B + (size_t)((bn << 7) + (wv << 3) + l8) * Ki + xcol;

#define STG_A(bufi, chunk, t)                          \
  gload_lds16(gA0 + (size_t)(chunk) * Ki + (t) * 64,   \
              &As[bufi][((chunk) << 6) + (wv << 9)])
#define STG_B(bufi, chunk, t)                          \
  gload_lds16(gB0 + (size_t)(chunk) * Ki + (t) * 64,   \
              &Bs[bufi][((chunk) << 6) + (wv << 9)])

  const bf16x8* Av = reinterpret_cast<const bf16x8*>(&As[0][0]);
  const bf16x8* Bv = reinterpret_cast<const bf16x8*>(&Bs[0][0]);

  f32x16 acc[2][2] = {};
  bf16x8 aF[4], bF[2][4];

  const int NT = Ki >> 6;   // 64-K tiles (host guarantees Ki%128==0, >=256)
  const int NI = NT >> 1;

  // ---- prologue: t0 all (8) + t1 {A-mt0, B} (6); VMW(6) forces t0 ----
  STG_A(0, 0, 0);  STG_A(0, 64, 0);   // t0 A-mt0 rows {0-31, 64-95}
  STG_A(0, 32, 0); STG_A(0, 96, 0);   // t0 A-mt1 rows {32-63, 96-127}
  STG_B(0, 0, 0);  STG_B(0, 32, 0);  STG_B(0, 64, 0);  STG_B(0, 96, 0);
  STG_A(1, 0, 1);  STG_A(1, 64, 1);   // t1 A-mt0
  STG_B(1, 0, 1);  STG_B(1, 32, 1);  STG_B(1, 64, 1);  STG_B(1, 96, 1);
  VMW(6);
  BARRIER();

#pragma unroll 1
  for (int i = 0; i < NI - 1; ++i) {
    const int t1 = 2 * i + 1, t2 = 2 * i + 2, t3 = 2 * i + 3;

    // P1: reads buf0 {B all (8), A-mt0 (4)} ; stage t1 A-mt1 (buf1,
    //     region last read prev-P4) ; MFMA mt0 ; BAR
    loadBall<0>(bF, Bv, wc, l31, erk);
    loadAmt<0, 0>(aF, Av, wr, l31, erk);
    STG_A(1, 32, t1); STG_A(1, 96, t1);
    quad2<0>(acc, aF, bF);
    BARRIER();

    // P2: reads buf0 A-mt1 (4) ; stage t2 A-mt0 + B (buf0 regions last
    //     read P1) ; MFMA mt1 ; VMW(6): forces t1's 8 ; BAR
    loadAmt<0, 1>(aF, Av, wr, l31, erk);
    STG_A(0, 0, t2); STG_A(0, 64, t2);
    STG_B(0, 0, t2); STG_B(0, 32, t2); STG_B(0, 64, t2); STG_B(0, 96, t2);
    quad2<1>(acc, aF, bF);
    VMW(6);
    BARRIER();

    // P3: reads buf1 {B all, A-mt0} ; stage t2 A-mt1 (buf0, last read P2)
    //     ; MFMA mt0 ; BAR
    loadBall<1>(bF, Bv, wc, l31, erk);
    loadAmt<1, 0>(aF, Av, wr, l31, erk);
    STG_A(0, 32, t2); STG_A(0, 96, t2);
    quad2<0>(acc, aF, bF);
    BARRIER();

    // P4: reads buf1 A-mt1 ; stage t3 A-mt0 + B (buf1 regions last read
    //     P3) ; MFMA mt1 ; VMW(6): forces t2's 8 ; BAR
    loadAmt<1, 1>(aF, Av, wr, l31, erk);
    STG_A(1, 0, t3); STG_A(1, 64, t3);
    STG_B(1, 0, t3); STG_B(1, 32, t3); STG_B(1, 64, t3); STG_B(1, 96, t3);
    quad2<1>(acc, aF, bF);
    VMW(6);
    BARRIER();
  }

  // ---- peeled last iteration (t0 = NT-2 buf0, t1 = NT-1 buf1) ----
  {
    const int t1 = NT - 1;
    // P1
    loadBall<0>(bF, Bv, wc, l31, erk);
    loadAmt<0, 0>(aF, Av, wr, l31, erk);
    STG_A(1, 32, t1); STG_A(1, 96, t1);
    quad2<0>(acc, aF, bF);
    BARRIER();
    // P2: drain everything -> t1 fully landed
    loadAmt<0, 1>(aF, Av, wr, l31, erk);
    quad2<1>(acc, aF, bF);
    VMW(0);
    BARRIER();
    // P3
    loadBall<1>(bF, Bv, wc, l31, erk);
    loadAmt<1, 0>(aF, Av, wr, l31, erk);
    quad2<0>(acc, aF, bF);
    BARRIER();
    // P4 (register-only)
    loadAmt<1, 1>(aF, Av, wr, l31, erk);
    quad2<1>(acc, aF, bF);
  }

  // ---- epilogue (32x32 C/D layout, m74/m101): col = lane&31,
  // row = (reg&3) + 8*(reg>>2) + 4*lk within each 32x32 tile.
  const int rowB = (bm << 7) + (wr << 6) + 4 * lk;
  const int colB = (bn << 7) + (wc << 6) + l31;
#pragma unroll
  for (int mt = 0; mt < 2; ++mt) {
    const int rBase = rowB + mt * 32;
#pragma unroll
    for (int nt = 0; nt < 2; ++nt) {
      const int col = colB + nt * 32;
      const float bv = bias[col];
#pragma unroll
      for (int reg = 0; reg < 16; ++reg) {
        const int row = rBase + (reg & 3) + 8 * (reg >> 2);
        C[(size_t)row * Ni + col] = acc[mt][nt][reg] * kScale + bv;
      }
    }
  }
}

// =====================================================================
// proven 128x128 fallback for non-conforming shapes
// =====================================================================
__global__ __launch_bounds__(256) void gemm_bf16_bias(
    const uint16_t* __restrict__ A, const uint16_t* __restrict__ B,
    const float* __restrict__ bias, float* __restrict__ C,
    int Mi, int Ni, int Ki) {
  __shared__ __align__(16) uint16_t As[128 * 32];
  __shared__ __align__(16) uint16_t Bs[128 * 32];

  const int tid  = threadIdx.x;
  const int lane = tid & 63;
  const int wv   = tid >> 6;
  const int wr   = wv >> 1;
  const int wc   = wv & 1;
  const int fr   = lane & 15;
  const int fh   = lane >> 4;

  const int nTilesN = Ni >> 7;
  const int nwg = gridDim.x;
  const int q = nwg >> 3, r = nwg & 7;
  const int xcd = (int)blockIdx.x & 7, orig = (int)blockIdx.x >> 3;
  const int swz = (xcd < r ? xcd * (q + 1) : r * (q + 1) + (xcd - r) * q) + orig;
  const int bm = swz / nTilesN;
  const int bn = swz % nTilesN;

  const int sRow = tid >> 2;
  const int sCol = (tid & 3) << 3;

  const uint16_t* gA0 = A + (size_t)(bm * 128 + sRow) * Ki + sCol;
  const uint16_t* gA1 = gA0 + (size_t)64 * Ki;
  const uint16_t* gB0 = B + (size_t)(bn * 128 + sRow) * Ki + sCol;
  const uint16_t* gB1 = gB0 + (size_t)64 * Ki;
  uint16_t* lA0 = &As[tid * 8];
  uint16_t* lA1 = &As[(256 + tid) * 8];
  uint16_t* lB0 = &Bs[tid * 8];
  uint16_t* lB1 = &Bs[(256 + tid) * 8];

  const bf16x8* Av = reinterpret_cast<const bf16x8*>(As);
  const bf16x8* Bv = reinterpret_cast<const bf16x8*>(Bs);

  f32x4 acc[4][4] = {};

  for (int k0 = 0; k0 < Ki; k0 += 32) {
    gload_lds16(gA0 + k0, lA0);
    gload_lds16(gA1 + k0, lA1);
    gload_lds16(gB0 + k0, lB0);
    gload_lds16(gB1 + k0, lB1);
    __syncthreads();

    bf16x8 af[4], bfr[4];
#pragma unroll
    for (int m = 0; m < 4; ++m) af[m] = Av[(wr * 64 + m * 16 + fr) * 4 + fh];
#pragma unroll
    for (int n = 0; n < 4; ++n) bfr[n] = Bv[(wc * 64 + n * 16 + fr) * 4 + fh];

#pragma unroll
    for (int m = 0; m < 4; ++m)
#pragma unroll
      for (int n = 0; n < 4; ++n)
        acc[m][n] = __builtin_amdgcn_mfma_f32_16x16x32_bf16(af[m], bfr[n],
                                                            acc[m][n], 0, 0, 0);
    __syncthreads();
  }

  const int rowBase = bm * 128 + wr * 64;
  const int colBase = bn * 128 + wc * 64;
#pragma unroll
  for (int n = 0; n < 4; ++n) {
    const int col = colBase + n * 16 + fr;
    const float bv = bias[col];
#pragma unroll
    for (int m = 0; m < 4; ++m) {
      const int row = rowBase + m * 16 + fh * 4;
#pragma unroll
      for (int j = 0; j < 4; ++j)
        C[(size_t)(row + j) * Ni + col] = acc[m][n][j] * kScale + bv;
    }
  }
}

// ---------- fallback: naive f32 ----------
__global__ void naive_gemm(const float* __restrict__ x, const float* __restrict__ w,
                           const float* __restrict__ bias, float* __restrict__ out,
                           int Mi, int Ni, int Ki) {
  long idx = (long)blockIdx.x * blockDim.x + threadIdx.x;
  if (idx >= (long)Mi * Ni) return;
  int m = (int)(idx / Ni), n = (int)(idx % Ni);
  float s = 0.f;
  for (int k = 0; k < Ki; ++k) s += x[(long)m * Ki + k] * w[(long)n * Ki + k];
  out[idx] = s * kScale + bias[n];
}

extern "C" void kernel_launch(void* const* d_in, const int* in_sizes, int n_in,
                              void* d_out, int out_size, void* d_ws, size_t ws_size,
                              hipStream_t stream) {
  const float* x    = (const float*)d_in[0];
  const float* w    = (const float*)d_in[1];
  const float* bias = (const float*)d_in[2];
  float* out = (float*)d_out;

  const int Ni = in_sizes[2];
  const int Ki = in_sizes[1] / Ni;
  const int Mi = in_sizes[0] / Ki;

  const size_t nx = (size_t)Mi * Ki;
  const size_t nw = (size_t)Ni * Ki;

  if (ws_size >= (nx + nw) * sizeof(uint16_t) && (Ki % 32) == 0 &&
      (Mi % 128) == 0 && (Ni % 128) == 0) {
    uint16_t* xb = (uint16_t*)d_ws;
    uint16_t* wb = xb + nx;

    if ((nx % 2048) == 0 && (nw % 2048) == 0) {
      long total8 = (long)((nx + nw) / 8);
      cvt_fused<<<(int)(total8 / 256), 256, 0, stream>>>(x, w, (uint4*)xb,
                                                         (long)(nx / 8));
    } else {
      cvt_f32_to_bf16<<<(int)(nx / 2048), 256, 0, stream>>>(x, (uint4*)xb);
      cvt_f32_to_bf16<<<(int)(nw / 2048), 256, 0, stream>>>(w, (uint4*)wb);
    }

    if ((Ki % 128) == 0 && Ki >= 256) {
      dim3 grid((Mi / 128) * (Ni / 128));
      gemm128_2ph<<<grid, 256, 0, stream>>>(xb, wb, bias, out, Mi, Ni, Ki);
    } else {
      dim3 grid((Mi / 128) * (Ni / 128));
      gemm_bf16_bias<<<grid, 256, 0, stream>>>(xb, wb, bias, out, Mi, Ni, Ki);
    }
  } else {
    long total = (long)Mi * Ni;
    naive_gemm<<<(int)((total + 255) / 256), 256, 0, stream>>>(x, w, bias, out,
                                                               Mi, Ni, Ki);
  }
}